// Round 3
// baseline (226.750 us; speedup 1.0000x reference)
//
#include <hip/hip_runtime.h>

#define DIM 128

// ws layout (all zeroed by a single 576-B memset node):
//   float num[128]   @ +0    (512 B)
//   float den        @ +512
//   uint  done_count @ +516

__global__ void fused_kernel(const int* __restrict__ user_idx,
                             const int* __restrict__ edge_src,
                             const int* __restrict__ edge_dst,
                             const int* __restrict__ edge_freq,
                             int E,
                             const float* __restrict__ poi,       // [P, DIM]
                             const float* __restrict__ user_emb,  // [U, DIM]
                             const float* __restrict__ fc_w,      // [DIM, 2*DIM]
                             const float* __restrict__ fc_b,      // [DIM]
                             float* __restrict__ num,             // [DIM]
                             float* __restrict__ den,             // [1]
                             unsigned int* __restrict__ done,     // [1]
                             float* __restrict__ out) {           // [DIM]
    const int uid = user_idx[0];
    const int lane = threadIdx.x & 63;
    const int gtid = blockIdx.x * blockDim.x + threadIdx.x;
    const int stride = gridDim.x * blockDim.x;
    const int E4 = E >> 2;
    const int4* __restrict__ src4 = (const int4*)edge_src;

    for (int i4 = gtid; i4 < E4; i4 += stride) {
        const int4 s = src4[i4];
        const bool any = (s.x == uid) | (s.y == uid) | (s.z == uid) | (s.w == uid);
        if (__any(any)) {                      // rare path (~32 of 3.2M edges)
            const int base = i4 * 4;
            const int sv[4] = {s.x, s.y, s.z, s.w};
#pragma unroll
            for (int j = 0; j < 4; ++j) {
                const bool m = (sv[j] == uid);
                int dst = 0, f = 0;
                if (m) { dst = edge_dst[base + j]; f = edge_freq[base + j]; }
                unsigned long long b = __ballot(m);
                while (b) {
                    const int sl = (int)__ffsll(b) - 1;
                    b &= b - 1;
                    const int   ddst = __shfl(dst, sl);
                    const float fv   = (float)__shfl(f, sl);
                    const float* row = poi + (size_t)ddst * DIM;   // 512-B row, coalesced
                    const float v0 = row[lane];
                    const float v1 = row[lane + 64];
                    atomicAdd(&num[lane],      fv * v0);
                    atomicAdd(&num[lane + 64], fv * v1);
                    if (lane == 0) atomicAdd(den, fv);
                }
            }
        }
    }
    // tail (E not multiple of 4) — absent for E=3.2M, kept for generality
    for (int i = E4 * 4 + gtid; i < E; i += stride) {
        if (edge_src[i] == uid) {
            const float fv = (float)edge_freq[i];
            const float* row = poi + (size_t)edge_dst[i] * DIM;
            for (int k = 0; k < DIM; ++k) atomicAdd(&num[k], fv * row[k]);
            atomicAdd(den, fv);
        }
    }

    // ---- last-block-done: the final block performs the epilogue ----
    __shared__ bool last_block;
    __shared__ float comb[2 * DIM];
    if (threadIdx.x == 0) {
        __threadfence();  // make this block's atomics globally visible (release)
        unsigned int old = __hip_atomic_fetch_add(done, 1u, __ATOMIC_ACQ_REL,
                                                  __HIP_MEMORY_SCOPE_AGENT);
        last_block = (old == gridDim.x - 1);
    }
    __syncthreads();
    if (!last_block) return;

    const int d = threadIdx.x;  // block has 256 threads; use 0..127
    if (d < DIM) {
        // agent-scope atomic loads: safe vs non-coherent per-XCD L2s
        const float nv = __hip_atomic_load(&num[d], __ATOMIC_RELAXED,
                                           __HIP_MEMORY_SCOPE_AGENT);
        const float dv = __hip_atomic_load(den, __ATOMIC_RELAXED,
                                           __HIP_MEMORY_SCOPE_AGENT);
        const float neigh = (dv > 0.0f) ? (nv / dv) : 0.0f;
        comb[d]       = user_emb[(size_t)uid * DIM + d];
        comb[DIM + d] = neigh;
    }
    __syncthreads();
    if (d < DIM) {
        const float4* __restrict__ w4 = (const float4*)(fc_w + (size_t)d * (2 * DIM));
        float acc = fc_b[d];
#pragma unroll 8
        for (int k = 0; k < (2 * DIM) / 4; ++k) {
            const float4 w = w4[k];
            acc += w.x * comb[4 * k + 0] + w.y * comb[4 * k + 1] +
                   w.z * comb[4 * k + 2] + w.w * comb[4 * k + 3];
        }
        out[d] = acc;
    }
}

extern "C" void kernel_launch(void* const* d_in, const int* in_sizes, int n_in,
                              void* d_out, int out_size, void* d_ws, size_t ws_size,
                              hipStream_t stream) {
    const int*   user_idx  = (const int*)d_in[0];
    const float* poi       = (const float*)d_in[1];
    const int*   edge_src  = (const int*)d_in[2];
    const int*   edge_dst  = (const int*)d_in[3];
    const int*   edge_freq = (const int*)d_in[4];
    const float* user_emb  = (const float*)d_in[5];
    const float* fc_w      = (const float*)d_in[6];
    const float* fc_b      = (const float*)d_in[7];
    float* out = (float*)d_out;

    const int E = in_sizes[2];

    char* ws = (char*)d_ws;
    float* num        = (float*)ws;            // 128 floats
    float* den        = (float*)(ws + 512);    // 1 float
    unsigned int* done = (unsigned int*)(ws + 516);

    // zero accumulators + done counter (ws is poisoned 0xAA before every launch)
    hipMemsetAsync(ws, 0, 576, stream);

    const int threads = 256;
    const int E4 = E >> 2;
    int blocks = (E4 + threads - 1) / threads;
    if (blocks < 1) blocks = 1;
    if (blocks > 65535) blocks = 65535;

    fused_kernel<<<blocks, threads, 0, stream>>>(
        user_idx, edge_src, edge_dst, edge_freq, E, poi,
        user_emb, fc_w, fc_b, num, den, done, out);
}

// Round 4
// 132.108 us; speedup vs baseline: 1.7164x; 1.7164x over previous
//
#include <hip/hip_runtime.h>

#define DIM 128

// ws layout: float num[128] (512 B) | float den (at +512) ; memset first 640 B to 0.
//
// NOTE (R3 post-mortem): do NOT fuse the epilogue via last-block-done here.
// The agent-scope release fence (__threadfence) per block forces an L2
// writeback on every one of ~3125 blocks (per-XCD L2s non-coherent on
// gfx950) -> kernel went 5-10us -> 103us. Two kernels + device-scope
// atomicAdd (coherent by default) is the fast structure.

__global__ void scan_accum_kernel(const int* __restrict__ user_idx,
                                  const int* __restrict__ edge_src,
                                  const int* __restrict__ edge_dst,
                                  const int* __restrict__ edge_freq,
                                  int E,
                                  const float* __restrict__ poi,   // [P, DIM]
                                  float* __restrict__ num,         // [DIM]
                                  float* __restrict__ den) {       // [1]
    const int uid = user_idx[0];
    const int lane = threadIdx.x & 63;
    const int gtid = blockIdx.x * blockDim.x + threadIdx.x;
    const int stride = gridDim.x * blockDim.x;
    const int E4 = E >> 2;
    const int4* __restrict__ src4 = (const int4*)edge_src;

    for (int i4 = gtid; i4 < E4; i4 += stride) {
        const int4 s = src4[i4];
        const bool any = (s.x == uid) | (s.y == uid) | (s.z == uid) | (s.w == uid);
        if (__any(any)) {                      // rare path (~32 of 3.2M edges)
            const int base = i4 * 4;
            const int sv[4] = {s.x, s.y, s.z, s.w};
#pragma unroll
            for (int j = 0; j < 4; ++j) {
                const bool m = (sv[j] == uid);
                int dst = 0, f = 0;
                if (m) { dst = edge_dst[base + j]; f = edge_freq[base + j]; }
                unsigned long long b = __ballot(m);
                while (b) {
                    const int sl = (int)__ffsll(b) - 1;
                    b &= b - 1;
                    const int   ddst = __shfl(dst, sl);
                    const float fv   = (float)__shfl(f, sl);
                    // whole wave loads the 128-float row: 2 floats/lane, coalesced
                    const float* row = poi + (size_t)ddst * DIM;
                    const float v0 = row[lane];
                    const float v1 = row[lane + 64];
                    atomicAdd(&num[lane],      fv * v0);
                    atomicAdd(&num[lane + 64], fv * v1);
                    if (lane == 0) atomicAdd(den, fv);
                }
            }
        }
    }
    // tail (E not multiple of 4) — absent for E=3.2M, kept for generality
    for (int i = E4 * 4 + gtid; i < E; i += stride) {
        if (edge_src[i] == uid) {
            const float fv = (float)edge_freq[i];
            const float* row = poi + (size_t)edge_dst[i] * DIM;
            for (int k = 0; k < DIM; ++k) atomicAdd(&num[k], fv * row[k]);
            atomicAdd(den, fv);
        }
    }
}

__global__ void __launch_bounds__(DIM)
finish_kernel(const int* __restrict__ user_idx,
              const float* __restrict__ user_emb,  // [U, DIM]
              const float* __restrict__ fc_w,      // [DIM, 2*DIM] row-major
              const float* __restrict__ fc_b,      // [DIM]
              const float* __restrict__ num,       // [DIM]
              const float* __restrict__ den,       // [1]
              float* __restrict__ out) {           // [DIM]
    __shared__ float comb[2 * DIM];
    const int d = threadIdx.x;  // 0..127

    const float dv = *den;
    const float neigh = (dv > 0.0f) ? (num[d] / dv) : 0.0f;

    const int uid = user_idx[0];
    comb[d]       = user_emb[(size_t)uid * DIM + d];
    comb[DIM + d] = neigh;
    __syncthreads();

    const float4* __restrict__ w4 = (const float4*)(fc_w + (size_t)d * (2 * DIM));
    float acc = fc_b[d];
#pragma unroll 8
    for (int k = 0; k < (2 * DIM) / 4; ++k) {
        const float4 w = w4[k];
        acc += w.x * comb[4 * k + 0] + w.y * comb[4 * k + 1] +
               w.z * comb[4 * k + 2] + w.w * comb[4 * k + 3];
    }
    out[d] = acc;
}

extern "C" void kernel_launch(void* const* d_in, const int* in_sizes, int n_in,
                              void* d_out, int out_size, void* d_ws, size_t ws_size,
                              hipStream_t stream) {
    const int*   user_idx  = (const int*)d_in[0];
    const float* poi       = (const float*)d_in[1];
    const int*   edge_src  = (const int*)d_in[2];
    const int*   edge_dst  = (const int*)d_in[3];
    const int*   edge_freq = (const int*)d_in[4];
    const float* user_emb  = (const float*)d_in[5];
    const float* fc_w      = (const float*)d_in[6];
    const float* fc_b      = (const float*)d_in[7];
    float* out = (float*)d_out;

    const int E = in_sizes[2];

    char* ws = (char*)d_ws;
    float* num = (float*)ws;           // 128 floats
    float* den = (float*)(ws + 512);   // 1 float

    // zero the accumulators (ws is poisoned 0xAA before every timed launch)
    hipMemsetAsync(ws, 0, 640, stream);

    const int threads = 256;
    const int E4 = E >> 2;
    int blocks = (E4 + threads - 1) / threads;
    if (blocks < 1) blocks = 1;
    if (blocks > 65535) blocks = 65535;

    scan_accum_kernel<<<blocks, threads, 0, stream>>>(
        user_idx, edge_src, edge_dst, edge_freq, E, poi, num, den);

    finish_kernel<<<1, DIM, 0, stream>>>(
        user_idx, user_emb, fc_w, fc_b, num, den, out);
}